// Round 6
// baseline (181.256 us; speedup 1.0000x reference)
//
#include <hip/hip_runtime.h>

#define MAXT 16
#define DDIM 1024
#define NTHREADS 256
#define TPW 4          // depths per wave (4 waves x 4 = 16 = MAXT)
#define SPB 8          // sites per block (software pipeline depth)

// Barrier that does NOT drain vmcnt: LDS-only wait + raw s_barrier.
// Global loads for the next pipelined site stay in flight across it.
#define LGKM_BAR() do { asm volatile("s_waitcnt lgkmcnt(0)" ::: "memory"); \
                        __builtin_amdgcn_s_barrier(); } while (0)

// Full wave64 sum via DPP (VALU pipe only, no DS ops). Result broadcast via readlane.
__device__ __forceinline__ float dpp_sum64(float x) {
    int v;
    v = __builtin_amdgcn_update_dpp(0, __float_as_int(x), 0x111, 0xf, 0xf, true);  // row_shr:1
    x += __int_as_float(v);
    v = __builtin_amdgcn_update_dpp(0, __float_as_int(x), 0x112, 0xf, 0xf, true);  // row_shr:2
    x += __int_as_float(v);
    v = __builtin_amdgcn_update_dpp(0, __float_as_int(x), 0x114, 0xf, 0xf, true);  // row_shr:4
    x += __int_as_float(v);
    v = __builtin_amdgcn_update_dpp(0, __float_as_int(x), 0x118, 0xf, 0xf, true);  // row_shr:8
    x += __int_as_float(v);
    v = __builtin_amdgcn_update_dpp(0, __float_as_int(x), 0x142, 0xa, 0xf, false); // row_bcast:15
    x += __int_as_float(v);
    v = __builtin_amdgcn_update_dpp(0, __float_as_int(x), 0x143, 0xc, 0xf, false); // row_bcast:31
    x += __int_as_float(v);
    return __int_as_float(__builtin_amdgcn_readlane(__float_as_int(x), 63));
}

// Branch-free site load: clamped depth index (masked t re-reads slice n1 ->
// L1 hit, owning wave of the same block reads it anyway). Unconditional loads
// let the compiler statically count vmcnt for the pipeline.
__device__ __forceinline__
void load_site(float4 (&e)[TPW][4], const float* __restrict__ ebase,
               size_t tStride, int wave, int n1)
{
#pragma unroll
    for (int tt = 0; tt < TPW; ++tt) {
        const int t  = wave + 4 * tt;          // interleaved ownership
        const int tl = t <= n1 ? t : n1;       // wave-uniform clamp
#pragma unroll
        for (int c = 0; c < 4; ++c)
            e[tt][c] = *reinterpret_cast<const float4*>(ebase + (size_t)tl * tStride + c * 256);
    }
}

__device__ __forceinline__
void process_site(const float4 (&e)[TPW][4], const float4 (&q)[4],
                  float* __restrict__ red, float (* __restrict__ part)[DDIM],
                  int wave, int lane, int tid, int dbase, int n_act,
                  float* __restrict__ osite)
{
    // Per-depth partials over this thread's 16 elements (compiler inserts
    // counted vmcnt waits for this site's loads here; next site's stay out).
    float ss[TPW], dt[TPW];
#pragma unroll
    for (int tt = 0; tt < TPW; ++tt) {
        float s = 0.f, d = 0.f;
#pragma unroll
        for (int c = 0; c < 4; ++c) {
            const float4 v = e[tt][c];
            s = fmaf(v.x, v.x, s); s = fmaf(v.y, v.y, s);
            s = fmaf(v.z, v.z, s); s = fmaf(v.w, v.w, s);
            d = fmaf(q[c].x, v.x, d); d = fmaf(q[c].y, v.y, d);
            d = fmaf(q[c].z, v.z, d); d = fmaf(q[c].w, v.w, d);
        }
        ss[tt] = s; dt[tt] = d;
    }

    // Wave64 reduction on the VALU pipe.
#pragma unroll
    for (int tt = 0; tt < TPW; ++tt) {
        ss[tt] = dpp_sum64(ss[tt]);
        dt[tt] = dpp_sum64(dt[tt]);
    }

    if (lane == 0) {
#pragma unroll
        for (int tt = 0; tt < TPW; ++tt) {
            const int t = wave + 4 * tt;
            red[t]        = ss[tt];
            red[MAXT + t] = dt[tt];
        }
    }
    LGKM_BAR();   // barrier 1: red[] visible; next-site global loads unaffected

    // Redundant per-thread softmax stats over all 16 depths.
    float lg[MAXT];
#pragma unroll
    for (int c = 0; c < 4; ++c) {
        const float4 rs = *reinterpret_cast<const float4*>(&red[c * 4]);
        const float4 rd = *reinterpret_cast<const float4*>(&red[MAXT + c * 4]);
        lg[c * 4 + 0] = rd.x * rsqrtf(rs.x * (1.f / DDIM) + 1e-5f);
        lg[c * 4 + 1] = rd.y * rsqrtf(rs.y * (1.f / DDIM) + 1e-5f);
        lg[c * 4 + 2] = rd.z * rsqrtf(rs.z * (1.f / DDIM) + 1e-5f);
        lg[c * 4 + 3] = rd.w * rsqrtf(rs.w * (1.f / DDIM) + 1e-5f);
    }
    float m = -3.0e38f;
#pragma unroll
    for (int t = 0; t < MAXT; ++t)
        if (t < n_act) m = fmaxf(m, lg[t]);
    float sum = 0.f;
#pragma unroll
    for (int t = 0; t < MAXT; ++t)
        if (t < n_act) sum += __expf(lg[t] - m);
    const float inv = 1.f / sum;

    // This wave's 4 weights (LDS runtime-address reads only; no dyn reg index).
    float wt[TPW];
#pragma unroll
    for (int tt = 0; tt < TPW; ++tt) {
        const int t = wave + 4 * tt;
        const float s_ = red[t];
        const float d_ = red[MAXT + t];
        const float l_ = d_ * rsqrtf(s_ * (1.f / DDIM) + 1e-5f);
        wt[tt] = (t < n_act) ? __expf(l_ - m) * inv : 0.f;
    }

    // Weighted partial over this wave's depths (masked t: wt==0).
    float4 acc[4];
#pragma unroll
    for (int c = 0; c < 4; ++c) acc[c] = make_float4(0.f, 0.f, 0.f, 0.f);
#pragma unroll
    for (int tt = 0; tt < TPW; ++tt) {
#pragma unroll
        for (int c = 0; c < 4; ++c) {
            acc[c].x = fmaf(wt[tt], e[tt][c].x, acc[c].x);
            acc[c].y = fmaf(wt[tt], e[tt][c].y, acc[c].y);
            acc[c].z = fmaf(wt[tt], e[tt][c].z, acc[c].z);
            acc[c].w = fmaf(wt[tt], e[tt][c].w, acc[c].w);
        }
    }
#pragma unroll
    for (int c = 0; c < 4; ++c)
        *reinterpret_cast<float4*>(&part[wave][c * 256 + dbase]) = acc[c];
    LGKM_BAR();   // barrier 2: part[] visible

    // Cross-wave combine: thread owns osite[tid*4 .. tid*4+3].
    const int od = tid * 4;
    const float4 r0 = *reinterpret_cast<const float4*>(&part[0][od]);
    const float4 r1 = *reinterpret_cast<const float4*>(&part[1][od]);
    const float4 r2 = *reinterpret_cast<const float4*>(&part[2][od]);
    const float4 r3 = *reinterpret_cast<const float4*>(&part[3][od]);
    float4 r;
    r.x = (r0.x + r1.x) + (r2.x + r3.x);
    r.y = (r0.y + r1.y) + (r2.y + r3.y);
    r.z = (r0.z + r1.z) + (r2.z + r3.z);
    r.w = (r0.w + r1.w) + (r2.w + r3.w);
    *reinterpret_cast<float4*>(osite + od) = r;
}

__global__ __launch_bounds__(NTHREADS, 2)
void attn_depth_kernel(const float* __restrict__ entries,
                       const float* __restrict__ proj,
                       const float* __restrict__ norm_scale,
                       const int* __restrict__ n_active_p,
                       const int* __restrict__ block_idx_p,
                       float* __restrict__ out,
                       int BS)
{
    const int tid   = threadIdx.x;
    const int wave  = tid >> 6;
    const int lane  = tid & 63;
    const int dbase = lane * 4;

    int n_act = *n_active_p;
    n_act = n_act < 1 ? 1 : (n_act > MAXT ? MAXT : n_act);
    const int n1 = n_act - 1;
    int row = *block_idx_p;
    row = row > (MAXT - 1) ? (MAXT - 1) : (row < 0 ? 0 : row);

    // q = proj[row] * norm_scale at this thread's d-elements (loop-invariant)
    float4 q[4];
#pragma unroll
    for (int c = 0; c < 4; ++c) {
        const float4 p  = *reinterpret_cast<const float4*>(proj + (size_t)row * DDIM + c * 256 + dbase);
        const float4 ns = *reinterpret_cast<const float4*>(norm_scale + c * 256 + dbase);
        q[c] = make_float4(p.x * ns.x, p.y * ns.y, p.z * ns.z, p.w * ns.w);
    }

    __shared__ float red[2 * MAXT];
    __shared__ float part[TPW][DDIM];

    const size_t tStride = (size_t)BS * DDIM;
    const size_t site0   = (size_t)blockIdx.x * SPB;

    // Clamped site indices (BS % SPB == 0 in practice; duplicates write
    // identical bytes if it ever isn't).
    size_t s_[SPB];
#pragma unroll
    for (int k = 0; k < SPB; ++k) {
        size_t s = site0 + (size_t)k;
        s_[k] = s < (size_t)BS ? s : (size_t)(BS - 1);
    }

    float4 eA[TPW][4], eB[TPW][4];
    load_site(eA, entries + s_[0] * DDIM + dbase, tStride, wave, n1);

#pragma unroll
    for (int p = 0; p < SPB / 2; ++p) {
        // Issue next site's loads BEFORE the current site's compute tail.
        load_site(eB, entries + s_[2 * p + 1] * DDIM + dbase, tStride, wave, n1);
        process_site(eA, q, red, part, wave, lane, tid, dbase, n_act,
                     out + s_[2 * p] * DDIM);
        if (p + 1 < SPB / 2)
            load_site(eA, entries + s_[2 * p + 2] * DDIM + dbase, tStride, wave, n1);
        process_site(eB, q, red, part, wave, lane, tid, dbase, n_act,
                     out + s_[2 * p + 1] * DDIM);
    }
}

extern "C" void kernel_launch(void* const* d_in, const int* in_sizes, int n_in,
                              void* d_out, int out_size, void* d_ws, size_t ws_size,
                              hipStream_t stream)
{
    const float* entries = (const float*)d_in[0];
    const float* proj    = (const float*)d_in[1];
    const float* nscale  = (const float*)d_in[2];
    const int*   n_act   = (const int*)d_in[3];
    const int*   bidx    = (const int*)d_in[4];
    float*       out     = (float*)d_out;

    const int BS   = out_size / DDIM;            // B*S = 16384
    const int nblk = (BS + SPB - 1) / SPB;       // 2048
    attn_depth_kernel<<<nblk, NTHREADS, 0, stream>>>(entries, proj, nscale,
                                                     n_act, bidx, out, BS);
}

// Round 7
// 162.919 us; speedup vs baseline: 1.1126x; 1.1126x over previous
//
#include <hip/hip_runtime.h>

#define MAXT 16
#define DDIM 1024
#define NTHREADS 256
#define TPW 4          // depths per wave (4 waves x 4 = 16 = MAXT)

// Full wave64 sum via DPP (VALU pipe only, no DS ops). Result broadcast via readlane.
__device__ __forceinline__ float dpp_sum64(float x) {
    int v;
    v = __builtin_amdgcn_update_dpp(0, __float_as_int(x), 0x111, 0xf, 0xf, true);  // row_shr:1
    x += __int_as_float(v);
    v = __builtin_amdgcn_update_dpp(0, __float_as_int(x), 0x112, 0xf, 0xf, true);  // row_shr:2
    x += __int_as_float(v);
    v = __builtin_amdgcn_update_dpp(0, __float_as_int(x), 0x114, 0xf, 0xf, true);  // row_shr:4
    x += __int_as_float(v);
    v = __builtin_amdgcn_update_dpp(0, __float_as_int(x), 0x118, 0xf, 0xf, true);  // row_shr:8
    x += __int_as_float(v);
    v = __builtin_amdgcn_update_dpp(0, __float_as_int(x), 0x142, 0xa, 0xf, false); // row_bcast:15
    x += __int_as_float(v);
    v = __builtin_amdgcn_update_dpp(0, __float_as_int(x), 0x143, 0xc, 0xf, false); // row_bcast:31
    x += __int_as_float(v);
    return __int_as_float(__builtin_amdgcn_readlane(__float_as_int(x), 63));
}

// 4 waves/SIMD (VGPR <= 128): peak register payload kept ~110 by not
// materializing the 16-wide logit array (two-pass softmax over LDS chunks).
__global__ __launch_bounds__(NTHREADS, 4)
void attn_depth_kernel(const float* __restrict__ entries,
                       const float* __restrict__ proj,
                       const float* __restrict__ norm_scale,
                       const int* __restrict__ n_active_p,
                       const int* __restrict__ block_idx_p,
                       float* __restrict__ out,
                       int BS)
{
    const int site = blockIdx.x;          // b*S + s
    const int tid  = threadIdx.x;
    const int wave = tid >> 6;
    const int lane = tid & 63;

    int n_act = *n_active_p;
    n_act = n_act < 1 ? 1 : (n_act > MAXT ? MAXT : n_act);
    int row = *block_idx_p;
    row = row > (MAXT - 1) ? (MAXT - 1) : (row < 0 ? 0 : row);

    // This thread's d-elements: d(c,j) = c*256 + lane*4 + j, c = 0..3
    const int dbase = lane * 4;

    const size_t tStride = (size_t)BS * DDIM;
    const float* ebase = entries + (size_t)site * DDIM + dbase;

    // Interleaved depth ownership: wave w owns t = w + 4*tt (balanced loads).
    float4 e[TPW][4];
#pragma unroll
    for (int tt = 0; tt < TPW; ++tt) {
        const int t = wave + 4 * tt;            // wave-uniform
        if (t < n_act) {
#pragma unroll
            for (int c = 0; c < 4; ++c)
                e[tt][c] = *reinterpret_cast<const float4*>(ebase + (size_t)t * tStride + c * 256);
        } else {
#pragma unroll
            for (int c = 0; c < 4; ++c)
                e[tt][c] = make_float4(0.f, 0.f, 0.f, 0.f);
        }
    }

    // q = proj[row] * norm_scale at this thread's d-elements (cached, tiny).
    // q dies after the dot pass -> not part of peak pressure later.
    float4 q[4];
#pragma unroll
    for (int c = 0; c < 4; ++c) {
        float4 p  = *reinterpret_cast<const float4*>(proj + (size_t)row * DDIM + c * 256 + dbase);
        float4 ns = *reinterpret_cast<const float4*>(norm_scale + c * 256 + dbase);
        q[c] = make_float4(p.x * ns.x, p.y * ns.y, p.z * ns.z, p.w * ns.w);
    }

    // Per-depth partials over this thread's 16 elements
    float ss[TPW], dt[TPW];
#pragma unroll
    for (int tt = 0; tt < TPW; ++tt) {
        float s = 0.f, d = 0.f;
#pragma unroll
        for (int c = 0; c < 4; ++c) {
            const float4 v = e[tt][c];
            s = fmaf(v.x, v.x, s); s = fmaf(v.y, v.y, s);
            s = fmaf(v.z, v.z, s); s = fmaf(v.w, v.w, s);
            d = fmaf(q[c].x, v.x, d); d = fmaf(q[c].y, v.y, d);
            d = fmaf(q[c].z, v.z, d); d = fmaf(q[c].w, v.w, d);
        }
        ss[tt] = s; dt[tt] = d;
    }

    // Wave64 reduction on the VALU pipe (DPP).
#pragma unroll
    for (int tt = 0; tt < TPW; ++tt) {
        ss[tt] = dpp_sum64(ss[tt]);
        dt[tt] = dpp_sum64(dt[tt]);
    }

    __shared__ float red[2 * MAXT];        // [0..15]=ss, [16..31]=dt (by t)
    __shared__ float part[TPW][DDIM];      // per-wave partial outputs (16 KB)

    if (lane == 0) {
#pragma unroll
        for (int tt = 0; tt < TPW; ++tt) {
            const int t = wave + 4 * tt;
            red[t]        = ss[tt];
            red[MAXT + t] = dt[tt];
        }
    }
    __syncthreads();

    // Two-pass softmax stats: no 16-wide register array, chunks recomputed
    // from LDS (keeps peak VGPR under the 128 cap for 4 waves/SIMD).
    float m = -3.0e38f;
#pragma unroll
    for (int c = 0; c < 4; ++c) {
        const float4 rs = *reinterpret_cast<const float4*>(&red[c * 4]);
        const float4 rd = *reinterpret_cast<const float4*>(&red[MAXT + c * 4]);
        const int t0 = c * 4;
        float l0 = rd.x * rsqrtf(rs.x * (1.f / DDIM) + 1e-5f);
        float l1 = rd.y * rsqrtf(rs.y * (1.f / DDIM) + 1e-5f);
        float l2 = rd.z * rsqrtf(rs.z * (1.f / DDIM) + 1e-5f);
        float l3 = rd.w * rsqrtf(rs.w * (1.f / DDIM) + 1e-5f);
        if (t0 + 0 < n_act) m = fmaxf(m, l0);
        if (t0 + 1 < n_act) m = fmaxf(m, l1);
        if (t0 + 2 < n_act) m = fmaxf(m, l2);
        if (t0 + 3 < n_act) m = fmaxf(m, l3);
    }
    float sum = 0.f;
#pragma unroll
    for (int c = 0; c < 4; ++c) {
        const float4 rs = *reinterpret_cast<const float4*>(&red[c * 4]);
        const float4 rd = *reinterpret_cast<const float4*>(&red[MAXT + c * 4]);
        const int t0 = c * 4;
        float l0 = rd.x * rsqrtf(rs.x * (1.f / DDIM) + 1e-5f);
        float l1 = rd.y * rsqrtf(rs.y * (1.f / DDIM) + 1e-5f);
        float l2 = rd.z * rsqrtf(rs.z * (1.f / DDIM) + 1e-5f);
        float l3 = rd.w * rsqrtf(rs.w * (1.f / DDIM) + 1e-5f);
        sum += (t0 + 0 < n_act) ? __expf(l0 - m) : 0.f;
        sum += (t0 + 1 < n_act) ? __expf(l1 - m) : 0.f;
        sum += (t0 + 2 < n_act) ? __expf(l2 - m) : 0.f;
        sum += (t0 + 3 < n_act) ? __expf(l3 - m) : 0.f;
    }
    const float inv = 1.f / sum;

    // This wave's 4 weights, recomputed from LDS at runtime ADDRESS only.
    float wt[TPW];
#pragma unroll
    for (int tt = 0; tt < TPW; ++tt) {
        const int t = wave + 4 * tt;
        const float s_ = red[t];
        const float d_ = red[MAXT + t];
        const float l_ = d_ * rsqrtf(s_ * (1.f / DDIM) + 1e-5f);
        wt[tt] = (t < n_act) ? __expf(l_ - m) * inv : 0.f;
    }

    // Weighted partial over this wave's depths (masked t: wt==0 and e==0).
    float4 acc[4];
#pragma unroll
    for (int c = 0; c < 4; ++c) acc[c] = make_float4(0.f, 0.f, 0.f, 0.f);
#pragma unroll
    for (int tt = 0; tt < TPW; ++tt) {
#pragma unroll
        for (int c = 0; c < 4; ++c) {
            acc[c].x = fmaf(wt[tt], e[tt][c].x, acc[c].x);
            acc[c].y = fmaf(wt[tt], e[tt][c].y, acc[c].y);
            acc[c].z = fmaf(wt[tt], e[tt][c].z, acc[c].z);
            acc[c].w = fmaf(wt[tt], e[tt][c].w, acc[c].w);
        }
    }
#pragma unroll
    for (int c = 0; c < 4; ++c)
        *reinterpret_cast<float4*>(&part[wave][c * 256 + dbase]) = acc[c];
    __syncthreads();

    // Cross-wave combine: thread owns out[tid*4 .. tid*4+3].
    const int od = tid * 4;
    float4 r0 = *reinterpret_cast<const float4*>(&part[0][od]);
    float4 r1 = *reinterpret_cast<const float4*>(&part[1][od]);
    float4 r2 = *reinterpret_cast<const float4*>(&part[2][od]);
    float4 r3 = *reinterpret_cast<const float4*>(&part[3][od]);
    float4 r;
    r.x = (r0.x + r1.x) + (r2.x + r3.x);
    r.y = (r0.y + r1.y) + (r2.y + r3.y);
    r.z = (r0.z + r1.z) + (r2.z + r3.z);
    r.w = (r0.w + r1.w) + (r2.w + r3.w);
    *reinterpret_cast<float4*>(out + (size_t)site * DDIM + od) = r;
}

extern "C" void kernel_launch(void* const* d_in, const int* in_sizes, int n_in,
                              void* d_out, int out_size, void* d_ws, size_t ws_size,
                              hipStream_t stream)
{
    const float* entries = (const float*)d_in[0];
    const float* proj    = (const float*)d_in[1];
    const float* nscale  = (const float*)d_in[2];
    const int*   n_act   = (const int*)d_in[3];
    const int*   bidx    = (const int*)d_in[4];
    float*       out     = (float*)d_out;

    const int BS = out_size / DDIM;   // B*S = 16384
    attn_depth_kernel<<<BS, NTHREADS, 0, stream>>>(entries, proj, nscale,
                                                   n_act, bidx, out, BS);
}